// Round 1
// baseline (95.926 us; speedup 1.0000x reference)
//
#include <hip/hip_runtime.h>
#include <math.h>

#define K_ 32
#define D_ 8
#define EPS_ 1e-6f
#define STRIDE_ 48   // 36 tri + 8 zm + 1 cst + 3 pad (16B alignment per k)

// ---------------------------------------------------------------------------
// Per-component precompute: K=32 threads, one component each.
// cov = tril(chol_var) @ tril(chol_var)^T + eps*I ; C = chol(cov);
// Cinv = C^{-1} (lower); zm = Cinv @ mean; cst = log_softmax(pi)_k
//        - 0.5*(logdet + D*log(2*pi)).
// Packed into cv[k*48 + ...]: [0..35] row-major lower-tri Cinv, [36..43] zm,
// [44] cst.
// ---------------------------------------------------------------------------
__global__ void gmm_precompute(const float* __restrict__ pi,
                               const float* __restrict__ means,
                               const float* __restrict__ chol,
                               float* __restrict__ cv) {
    int k = threadIdx.x;
    if (k >= K_) return;

    float L[D_][D_];
#pragma unroll
    for (int i = 0; i < D_; ++i)
#pragma unroll
        for (int j = 0; j < D_; ++j)
            L[i][j] = (j <= i) ? chol[k * D_ * D_ + i * D_ + j] : 0.f;

    // cov (lower triangle only)
    float cov[D_][D_];
#pragma unroll
    for (int i = 0; i < D_; ++i)
#pragma unroll
        for (int j = 0; j < D_; ++j) {
            float s = 0.f;
            if (j <= i) {
#pragma unroll
                for (int m = 0; m < D_; ++m) s += L[i][m] * L[j][m];
                if (i == j) s += EPS_;
            }
            cov[i][j] = s;
        }

    // Cholesky: C lower, cov = C C^T
    float C[D_][D_];
#pragma unroll
    for (int i = 0; i < D_; ++i)
#pragma unroll
        for (int j = 0; j < D_; ++j) C[i][j] = 0.f;
#pragma unroll
    for (int j = 0; j < D_; ++j) {
        float s = cov[j][j];
#pragma unroll
        for (int m = 0; m < D_; ++m)
            if (m < j) s -= C[j][m] * C[j][m];
        float cjj = sqrtf(s);
        C[j][j] = cjj;
        float inv = 1.f / cjj;
#pragma unroll
        for (int i = 0; i < D_; ++i)
            if (i > j) {
                float t = cov[i][j];
#pragma unroll
                for (int m = 0; m < D_; ++m)
                    if (m < j) t -= C[i][m] * C[j][m];
                C[i][j] = t * inv;
            }
    }

    float logdet = 0.f;
#pragma unroll
    for (int i = 0; i < D_; ++i) logdet += __logf(C[i][i]);
    logdet *= 2.f;

    // Inverse of lower-triangular C (forward substitution per column)
    float Ci[D_][D_];
#pragma unroll
    for (int i = 0; i < D_; ++i)
#pragma unroll
        for (int j = 0; j < D_; ++j) Ci[i][j] = 0.f;
#pragma unroll
    for (int j = 0; j < D_; ++j) {
        Ci[j][j] = 1.f / C[j][j];
#pragma unroll
        for (int i = 0; i < D_; ++i)
            if (i > j) {
                float s = 0.f;
#pragma unroll
                for (int m = 0; m < D_; ++m)
                    if (m >= j && m < i) s += C[i][m] * Ci[m][j];
                Ci[i][j] = -s / C[i][i];
            }
    }

    // zm = Ci @ mean_k
    float zm[D_];
#pragma unroll
    for (int i = 0; i < D_; ++i) {
        float s = 0.f;
#pragma unroll
        for (int j = 0; j < D_; ++j)
            if (j <= i) s += Ci[i][j] * means[k * D_ + j];
        zm[i] = s;
    }

    // log_softmax(pi)_k — every thread redundantly reduces all K (K tiny)
    float mx = pi[0];
#pragma unroll
    for (int t = 1; t < K_; ++t) mx = fmaxf(mx, pi[t]);
    float se = 0.f;
#pragma unroll
    for (int t = 0; t < K_; ++t) se += __expf(pi[t] - mx);
    float lse = mx + __logf(se);

    const float LOG2PI = 1.8378770664093453f;
    float cst = (pi[k] - lse) - 0.5f * (logdet + (float)D_ * LOG2PI);

    float* p = cv + k * STRIDE_;
    int t = 0;
#pragma unroll
    for (int i = 0; i < D_; ++i)
#pragma unroll
        for (int j = 0; j < D_; ++j)
            if (j <= i) p[t++] = Ci[i][j];
#pragma unroll
    for (int i = 0; i < D_; ++i) p[36 + i] = zm[i];
    p[44] = cst;
    p[45] = 0.f; p[46] = 0.f; p[47] = 0.f;
}

// ---------------------------------------------------------------------------
// Main kernel: one thread per sample n. K-loop fully unrolled; per-k constants
// are wave-uniform -> compiler emits s_load (scalar pipe + scalar cache),
// costing zero VALU slots. wll[32] in VGPRs for two-pass logsumexp.
// ---------------------------------------------------------------------------
__global__ __launch_bounds__(256) void gmm_main(const float* __restrict__ x,
                                                const float* __restrict__ cv,
                                                float* __restrict__ out,
                                                int N) {
    int n = blockIdx.x * blockDim.x + threadIdx.x;
    if (n >= N) return;

    const float4* x4 = (const float4*)x + (size_t)n * 2;
    float4 a = x4[0];
    float4 b = x4[1];
    float xv[D_] = {a.x, a.y, a.z, a.w, b.x, b.y, b.z, b.w};

    float wll[K_];
#pragma unroll
    for (int k = 0; k < K_; ++k) {
        const float* __restrict__ p = cv + k * STRIDE_;
        float maha = 0.f;
        int t = 0;
#pragma unroll
        for (int i = 0; i < D_; ++i) {
            float z = -p[36 + i];  // start at -zm_i
#pragma unroll
            for (int j = 0; j <= i; ++j) z = fmaf(p[t + j], xv[j], z);
            t += i + 1;
            maha = fmaf(z, z, maha);
        }
        wll[k] = fmaf(maha, -0.5f, p[44]);
    }

    float m = wll[0];
#pragma unroll
    for (int k = 1; k < K_; ++k) m = fmaxf(m, wll[k]);
    float s = 0.f;
#pragma unroll
    for (int k = 0; k < K_; ++k) s += __expf(wll[k] - m);
    out[n] = m + __logf(s);
}

extern "C" void kernel_launch(void* const* d_in, const int* in_sizes, int n_in,
                              void* d_out, int out_size, void* d_ws, size_t ws_size,
                              hipStream_t stream) {
    const float* x     = (const float*)d_in[0];
    const float* pi    = (const float*)d_in[1];
    const float* means = (const float*)d_in[2];
    const float* chol  = (const float*)d_in[3];
    float* out = (float*)d_out;
    float* cv  = (float*)d_ws;  // needs K_*STRIDE_*4 = 6144 bytes

    int N = in_sizes[0] / D_;

    gmm_precompute<<<1, 64, 0, stream>>>(pi, means, chol, cv);
    gmm_main<<<(N + 255) / 256, 256, 0, stream>>>(x, cv, out, N);
}